// Round 7
// baseline (260.719 us; speedup 1.0000x reference)
//
#include <hip/hip_runtime.h>
#include <hip/hip_bf16.h>
#include <math.h>

#define N_NODES 50000
#define E_RAW   800000
#define E_TOT   850000
#define NEG_SLOPE 0.2f
#define CAP 64   // ELL slots per node; deg = Poisson(16)+1, P(>64) ~ 1e-13

typedef __attribute__((ext_vector_type(8))) short short8;
typedef __attribute__((ext_vector_type(4))) float f32x4;

__device__ __forceinline__ short f2bf(float f) {
    __hip_bfloat16 h = __float2bfloat16(f);
    return *reinterpret_cast<short*>(&h);
}
__device__ __forceinline__ unsigned int f2bfu(float f) {
    __hip_bfloat16 h = __float2bfloat16(f);
    return (unsigned int)*reinterpret_cast<unsigned short*>(&h);
}
__device__ __forceinline__ float bflo(unsigned int u) {
    return __uint_as_float(u << 16);
}
__device__ __forceinline__ float bfhi(unsigned int u) {
    return __uint_as_float(u & 0xffff0000u);
}

// ============ W -> B-fragment-order bf16 swizzle (device body) ============
template<int K, int N>
__device__ __forceinline__ void wf_body(
        int blk, const float* __restrict__ W, short* __restrict__ Wf) {
    constexpr int NT = N / 16;
    const int idx = blk * 256 + threadIdx.x;
    if (idx >= K * N) return;
    const int j  = idx & 7;
    const int n  = (idx >> 3) & 15;
    const int q  = (idx >> 7) & 3;
    const int t  = (idx >> 9) % NT;
    const int kc = idx / (512 * NT);
    const int k   = kc * 32 + q * 8 + j;
    const int col = t * 16 + n;
    Wf[idx] = f2bf(W[(size_t)k * N + col]);
}

// both weight swizzles in one launch
__global__ __launch_bounds__(256) void gat_wf2x_kernel(
        const float* __restrict__ W1, short* __restrict__ Wf1,
        const float* __restrict__ W2, short* __restrict__ Wf2) {
    const int b = blockIdx.x;
    if (b < 128) wf_body<256, 128>(b, W1, Wf1);
    else         wf_body<128, 64>(b - 128, W2, Wf2);
}

// ============ MFMA GEMM + fused attention scores (device body) ============
template<int K, int N, bool BF16_IN>
__device__ __forceinline__ void gemm_att_body(
        const int blk,
        const float* __restrict__ xf, const short* __restrict__ xb,
        const short* __restrict__ Wf,
        const float* __restrict__ att_src, const float* __restrict__ att_dst,
        short* __restrict__ h_bf,
        float* __restrict__ a_src, float* __restrict__ a_dst) {
    constexpr int NT = N / 16;
    constexpr int KC = K / 32;
    const int tid  = threadIdx.x;
    const int lane = tid & 63;
    const int wv   = tid >> 6;
    const int mrow = lane & 15;
    const int q    = lane >> 4;

    const int row0 = blk * 64 + wv * 16;
    const int rowA = row0 + mrow;
    const int rowAc = rowA < N_NODES ? rowA : 0;

    f32x4 acc[NT];
    #pragma unroll
    for (int t = 0; t < NT; ++t) acc[t] = f32x4{0.f, 0.f, 0.f, 0.f};

    #pragma unroll
    for (int kc = 0; kc < KC; ++kc) {
        short8 a;
        if (BF16_IN) {
            a = *(const short8*)&xb[(size_t)rowAc * K + kc * 32 + q * 8];
        } else {
            const float4 f0 = *(const float4*)&xf[(size_t)rowAc * K + kc * 32 + q * 8];
            const float4 f1 = *(const float4*)&xf[(size_t)rowAc * K + kc * 32 + q * 8 + 4];
            a[0] = f2bf(f0.x); a[1] = f2bf(f0.y); a[2] = f2bf(f0.z); a[3] = f2bf(f0.w);
            a[4] = f2bf(f1.x); a[5] = f2bf(f1.y); a[6] = f2bf(f1.z); a[7] = f2bf(f1.w);
        }
        #pragma unroll
        for (int t = 0; t < NT; ++t) {
            const short8 b = *(const short8*)&Wf[((size_t)(kc * NT + t) * 64 + lane) * 8];
            acc[t] = __builtin_amdgcn_mfma_f32_16x16x32_bf16(a, b, acc[t], 0, 0, 0);
        }
    }

    // D layout: col = mrow, row = q*4 + r
    #pragma unroll
    for (int r = 0; r < 4; ++r) {
        const int rowD = row0 + q * 4 + r;
        float ps = 0.0f, pd = 0.0f;
        #pragma unroll
        for (int t = 0; t < NT; ++t) {
            const int col = t * 16 + mrow;
            ps = fmaf(acc[t][r], att_src[col], ps);
            pd = fmaf(acc[t][r], att_dst[col], pd);
        }
        #pragma unroll
        for (int off = 8; off > 0; off >>= 1) {
            ps += __shfl_xor(ps, off);
            pd += __shfl_xor(pd, off);
        }
        if (rowD < N_NODES) {
            if (mrow == 0) { a_src[rowD] = ps; a_dst[rowD] = pd; }
            #pragma unroll
            for (int t = 0; t < NT; ++t)
                h_bf[(size_t)rowD * N + t * 16 + mrow] = f2bf(acc[t][r]);
        }
    }
}

// ===== fat kernel: layer-1 GEMM (blocks [0,GB)) + ELL scatter (blocks [GB,..)) =====
template<int K, int N>
__global__ __launch_bounds__(256) void gat_fat1_kernel(
        const float* __restrict__ xf, const short* __restrict__ Wf,
        const float* __restrict__ att_src, const float* __restrict__ att_dst,
        short* __restrict__ h_bf,
        float* __restrict__ a_src, float* __restrict__ a_dst,
        const int* __restrict__ ei, int* __restrict__ cnt,
        int* __restrict__ srcs, int GB) {
    if ((int)blockIdx.x < GB) {
        gemm_att_body<K, N, false>(blockIdx.x, xf, nullptr, Wf,
                                   att_src, att_dst, h_bf, a_src, a_dst);
    } else {
        const int i = (blockIdx.x - GB) * 256 + threadIdx.x;
        if (i >= E_TOT) return;
        int s, d;
        if (i < E_RAW) { s = ei[i]; d = ei[E_RAW + i]; }
        else           { s = d = i - E_RAW; }
        const int c = atomicAdd(&cnt[d], 1);
        if (c < CAP) srcs[(d << 6) + c] = s;
    }
}

// ===== standalone GEMM (layer 2) =====
template<int K, int N, bool BF16_IN>
__global__ __launch_bounds__(256) void gat_gemm_att_kernel(
        const float* __restrict__ xf, const short* __restrict__ xb,
        const short* __restrict__ Wf,
        const float* __restrict__ att_src, const float* __restrict__ att_dst,
        short* __restrict__ h_bf,
        float* __restrict__ a_src, float* __restrict__ a_dst) {
    gemm_att_body<K, N, BF16_IN>(blockIdx.x, xf, xb, Wf,
                                 att_src, att_dst, h_bf, a_src, a_dst);
}

// ===== fused per-dst softmax + aggregation (ELL, one wave per dst) =====
// Phase A: lane j owns edge j; alpha in registers (deg <= CAP=64).
// Phase B: SLOTS edges/iter; LPR=64/SLOTS lanes per row, 32B (2 x uint4) per
// lane per edge -> 8 (N=128) / 16 (N=64) rows in flight.
template<int N, int SLOTS, bool LSM>
__global__ __launch_bounds__(256) void gat_aggr_kernel(
        const int* __restrict__ cnt, const int* __restrict__ srcs,
        const float* __restrict__ a_src, const float* __restrict__ a_dst,
        const unsigned short* __restrict__ h_bf, const float* __restrict__ bias,
        float* __restrict__ outf, uint4* __restrict__ outb) {
    constexpr int LPR = 64 / SLOTS;          // lanes per row (8 or 4)
    const int lane = threadIdx.x & 63;
    const int wave = threadIdx.x >> 6;
    const int d = blockIdx.x * 4 + wave;
    if (d >= N_NODES) return;
    const int beg = d << 6;                  // ELL base
    int deg = cnt[d];
    deg = deg < CAP ? deg : CAP;
    const float ad = a_dst[d];

    // ---- phase A: per-lane alpha ----
    const int sreg = srcs[beg + (lane < deg ? lane : 0)];
    float e;
    if (lane < deg) {
        float t = a_src[sreg] + ad;
        e = t > 0.0f ? t : NEG_SLOPE * t;
    } else {
        e = -1e30f;
    }
    float m = e;
    #pragma unroll
    for (int off = 32; off > 0; off >>= 1) m = fmaxf(m, __shfl_xor(m, off));
    const float anum = __expf(e - m);        // 0 for invalid lanes
    float ss = anum;
    #pragma unroll
    for (int off = 32; off > 0; off >>= 1) ss += __shfl_xor(ss, off);
    const float areg = anum / ss;            // lane j's alpha

    // ---- phase B ----
    const int g = lane / LPR;                // edge slot
    const int p = lane % LPR;                // position within row
    float acc[16];
    #pragma unroll
    for (int c = 0; c < 16; ++c) acc[c] = 0.0f;

    for (int j = 0; j < deg; j += SLOTS) {
        const int eidx = j + g;
        const int s    = __shfl(sreg, eidx & 63);
        float alpha    = __shfl(areg, eidx & 63);
        if (eidx >= deg) alpha = 0.0f;
        const unsigned short* hp = h_bf + (size_t)s * N + p * 16;  // 32B chunk
        const uint4 h0 = *(const uint4*)hp;
        const uint4 h1 = *(const uint4*)(hp + 8);
        acc[0]  = fmaf(alpha, bflo(h0.x), acc[0]);
        acc[1]  = fmaf(alpha, bfhi(h0.x), acc[1]);
        acc[2]  = fmaf(alpha, bflo(h0.y), acc[2]);
        acc[3]  = fmaf(alpha, bfhi(h0.y), acc[3]);
        acc[4]  = fmaf(alpha, bflo(h0.z), acc[4]);
        acc[5]  = fmaf(alpha, bfhi(h0.z), acc[5]);
        acc[6]  = fmaf(alpha, bflo(h0.w), acc[6]);
        acc[7]  = fmaf(alpha, bfhi(h0.w), acc[7]);
        acc[8]  = fmaf(alpha, bflo(h1.x), acc[8]);
        acc[9]  = fmaf(alpha, bfhi(h1.x), acc[9]);
        acc[10] = fmaf(alpha, bflo(h1.y), acc[10]);
        acc[11] = fmaf(alpha, bfhi(h1.y), acc[11]);
        acc[12] = fmaf(alpha, bflo(h1.z), acc[12]);
        acc[13] = fmaf(alpha, bfhi(h1.z), acc[13]);
        acc[14] = fmaf(alpha, bflo(h1.w), acc[14]);
        acc[15] = fmaf(alpha, bfhi(h1.w), acc[15]);
    }

    // reduce across edge-slot groups (lanes with same p)
    #pragma unroll
    for (int c = 0; c < 16; ++c) {
        #pragma unroll
        for (int off = LPR; off < 64; off <<= 1)
            acc[c] += __shfl_xor(acc[c], off);
    }

    // ---- epilogue ----
    if (LSM) {
        // N == 64, LPR == 4: lane p holds cols [p*16, p*16+16)
        float v[16];
        #pragma unroll
        for (int c = 0; c < 16; ++c) v[c] = acc[c] + bias[p * 16 + c];
        float mm = v[0];
        #pragma unroll
        for (int c = 1; c < 16; ++c) mm = fmaxf(mm, v[c]);
        mm = fmaxf(mm, __shfl_xor(mm, 1));
        mm = fmaxf(mm, __shfl_xor(mm, 2));
        float es = 0.0f;
        #pragma unroll
        for (int c = 0; c < 16; ++c) es += __expf(v[c] - mm);
        es += __shfl_xor(es, 1);
        es += __shfl_xor(es, 2);
        const float ls = mm + logf(es);
        if (lane < 4) {
            #pragma unroll
            for (int i = 0; i < 4; ++i) {
                float4 o;
                o.x = v[i * 4 + 0] - ls; o.y = v[i * 4 + 1] - ls;
                o.z = v[i * 4 + 2] - ls; o.w = v[i * 4 + 3] - ls;
                *(float4*)&outf[(size_t)d * N + p * 16 + i * 4] = o;
            }
        }
    } else {
        // N == 128, LPR == 8: bias + relu, pack bf16; lanes 0..7 write 32B
        if (lane < 8) {
            float v[16];
            #pragma unroll
            for (int c = 0; c < 16; ++c) {
                v[c] = acc[c] + bias[p * 16 + c];
                v[c] = fmaxf(v[c], 0.0f);
            }
            uint4 pk0, pk1;
            pk0.x = f2bfu(v[0])  | (f2bfu(v[1])  << 16);
            pk0.y = f2bfu(v[2])  | (f2bfu(v[3])  << 16);
            pk0.z = f2bfu(v[4])  | (f2bfu(v[5])  << 16);
            pk0.w = f2bfu(v[6])  | (f2bfu(v[7])  << 16);
            pk1.x = f2bfu(v[8])  | (f2bfu(v[9])  << 16);
            pk1.y = f2bfu(v[10]) | (f2bfu(v[11]) << 16);
            pk1.z = f2bfu(v[12]) | (f2bfu(v[13]) << 16);
            pk1.w = f2bfu(v[14]) | (f2bfu(v[15]) << 16);
            outb[(size_t)d * 16 + p * 2]     = pk0;
            outb[(size_t)d * 16 + p * 2 + 1] = pk1;
        }
    }
}

extern "C" void kernel_launch(void* const* d_in, const int* in_sizes, int n_in,
                              void* d_out, int out_size, void* d_ws, size_t ws_size,
                              hipStream_t stream) {
    const float* x        = (const float*)d_in[0];
    const int*   ei       = (const int*)  d_in[1];
    const float* W1       = (const float*)d_in[2];
    const float* att_src1 = (const float*)d_in[3];
    const float* att_dst1 = (const float*)d_in[4];
    const float* b1       = (const float*)d_in[5];
    const float* W2       = (const float*)d_in[6];
    const float* att_src2 = (const float*)d_in[7];
    const float* att_dst2 = (const float*)d_in[8];
    const float* b2       = (const float*)d_in[9];
    float* out = (float*)d_out;
    float* ws  = (float*)d_ws;

    // workspace layout (float units; 16B alignment holds throughout)
    float* a_src1 = ws;                        //  50,000
    float* a_dst1 = a_src1 + 50000;
    float* a_src2 = a_dst1 + 50000;
    float* a_dst2 = a_src2 + 50000;
    int*   cnt    = (int*)(a_dst2 + 50000);    //  50,000  (zeroed)
    int*   srcs   = cnt + 50000;               //  50,000 * 64 ELL
    short* hbf1   = (short*)(srcs + 50000 * CAP);   // 6,400,000 bf16
    short* agg1b  = hbf1  + 6400000;           // 6,400,000 bf16
    short* Wf1    = agg1b + 6400000;           //    32,768 bf16
    short* Wf2    = Wf1   + 32768;             //     8,192 bf16
    short* hbf2   = hbf1;                      // alias: hbf1 dead after aggr1

    hipMemsetAsync(cnt, 0, (size_t)50000 * 4, stream);

    const int EB = (E_TOT + 255) / 256;        // 3321 scatter blocks
    const int GB = (N_NODES + 63) / 64;        // 782 gemm blocks

    // ---- weight swizzles (one kernel) ----
    gat_wf2x_kernel<<<160, 256, 0, stream>>>(W1, Wf1, W2, Wf2);

    // ---- layer-1 GEMM + ELL scatter, fused ----
    gat_fat1_kernel<256, 128><<<GB + EB, 256, 0, stream>>>(
        x, Wf1, att_src1, att_dst1, hbf1, a_src1, a_dst1,
        ei, cnt, srcs, GB);

    // ---- layer-1 aggregation (8 rows in flight) ----
    gat_aggr_kernel<128, 8, false><<<12500, 256, 0, stream>>>(
        cnt, srcs, a_src1, a_dst1, (const unsigned short*)hbf1, b1,
        nullptr, (uint4*)agg1b);

    // ---- layer 2 ----
    gat_gemm_att_kernel<128, 64, true><<<GB, 256, 0, stream>>>(
        nullptr, agg1b, Wf2, att_src2, att_dst2, hbf2, a_src2, a_dst2);
    gat_aggr_kernel<64, 16, true><<<12500, 256, 0, stream>>>(
        cnt, srcs, a_src2, a_dst2, (const unsigned short*)hbf2, b2,
        out, nullptr);
}